// Round 1
// baseline (1162.318 us; speedup 1.0000x reference)
//
#include <hip/hip_runtime.h>
#include <math.h>

#define T_LEN 8192
#define N_B   128
#define N_F   8
#define NLAGS 24
#define EPSN  1e-8

__device__ __forceinline__ double wred(double v) {
    #pragma unroll
    for (int o = 32; o > 0; o >>= 1) v += __shfl_down(v, o, 64);
    return v;
}

__global__ __launch_bounds__(256)
void autocorr_batch_kernel(const float* __restrict__ seq,
                           const float* __restrict__ lw,
                           const float* __restrict__ si,
                           double* __restrict__ ws) {
    __shared__ float  sn[T_LEN];
    __shared__ double s4[2][4];
    __shared__ double sxy[NLAGS][4];
    __shared__ double sbc[2];  // mean, inv(std+eps)

    const int b    = blockIdx.x;
    const int tid  = threadIdx.x;
    const int wave = tid >> 6;
    const int lane = tid & 63;
    const size_t base = (size_t)b * T_LEN * N_F;

    // ---- load feature-0 column (strided), accumulate raw sum / sumsq ----
    float r[32];
    double s = 0.0, q = 0.0;
    #pragma unroll
    for (int i = 0; i < 32; i++) {
        int t = i * 256 + tid;
        float v = seq[base + (size_t)t * N_F];
        r[i] = v;
        s += v;
        q += (double)v * (double)v;
    }
    s = wred(s); q = wred(q);
    if (lane == 0) { s4[0][wave] = s; s4[1][wave] = q; }
    __syncthreads();
    if (tid == 0) {
        double S = s4[0][0] + s4[0][1] + s4[0][2] + s4[0][3];
        double Q = s4[1][0] + s4[1][1] + s4[1][2] + s4[1][3];
        double mean = S / (double)T_LEN;
        double var  = (Q - S * S / (double)T_LEN) / (double)(T_LEN - 1);
        sbc[0] = mean;
        sbc[1] = 1.0 / (sqrt(var) + EPSN);
    }
    __syncthreads();
    const double mean = sbc[0];
    const double inv  = sbc[1];

    // ---- normalize to fp32 (matches reference seqn), stage to LDS,
    //      accumulate S_all/Q_all of the *rounded* fp32 values ----
    s = 0.0; q = 0.0;
    #pragma unroll
    for (int i = 0; i < 32; i++) {
        float f = (float)(((double)r[i] - mean) * inv);
        r[i] = f;
        sn[i * 256 + tid] = f;
        s += f;
        q += (double)f * (double)f;
    }
    s = wred(s); q = wred(q);
    if (lane == 0) { s4[0][wave] = s; s4[1][wave] = q; }
    __syncthreads();   // covers s4 writes AND all sn[] writes

    double S_all = 0.0, Q_all = 0.0;
    if (tid == 0) {
        S_all = s4[0][0] + s4[0][1] + s4[0][2] + s4[0][3];
        Q_all = s4[1][0] + s4[1][1] + s4[1][2] + s4[1][3];
    }

    // ---- per-lag cross-products: only sum(x*y) needs a full reduction ----
    #pragma unroll 1
    for (int lag = 1; lag <= NLAGS; lag++) {
        double acc = 0.0;
        #pragma unroll
        for (int i = 0; i < 32; i++) {
            int t = i * 256 + tid;
            if (t < T_LEN - lag)
                acc += (double)r[i] * (double)sn[t + lag];
        }
        acc = wred(acc);
        if (lane == 0) sxy[lag - 1][wave] = acc;
    }
    __syncthreads();

    // ---- thread-0 tail: window sums via prefix/suffix, Pearson, softmax ----
    if (tid == 0) {
        double m = -1e300;
        for (int l = 0; l < NLAGS; l++) { double x = (double)lw[l]; if (x > m) m = x; }
        double wsum = 0.0;
        for (int l = 0; l < NLAGS; l++) wsum += exp((double)lw[l] - m);

        double pre_s = 0.0, pre_q = 0.0, suf_s = 0.0, suf_q = 0.0, v = 0.0;
        for (int lag = 1; lag <= NLAGS; lag++) {
            float fp = sn[lag - 1];
            float fs = sn[T_LEN - lag];
            pre_s += fp; pre_q += (double)fp * (double)fp;
            suf_s += fs; suf_q += (double)fs * (double)fs;
            double n  = (double)(T_LEN - lag);
            double sx = S_all - suf_s;   // sum over x window [0, T-lag)
            double sy = S_all - pre_s;   // sum over y window [lag, T)
            double qx = Q_all - suf_q;
            double qy = Q_all - pre_q;
            double xy = sxy[lag - 1][0] + sxy[lag - 1][1] + sxy[lag - 1][2] + sxy[lag - 1][3];
            double num = xy - sx * sy / n;
            double dx  = qx - sx * sx / n;
            double dy  = qy - sy * sy / n;
            double den = sqrt(dx) * sqrt(dy);
            double rr  = num / den;
            rr = fmin(1.0, fmax(-1.0, rr));
            double wgt = exp((double)lw[lag - 1] - m) / wsum;
            v += rr * wgt;
            if (lag == 12) v += rr * (double)si[0];
            if (lag == 24) v += rr * (double)si[1];
        }
        ws[b] = v;
    }
}

__global__ __launch_bounds__(64)
void final_reduce_kernel(const double* __restrict__ ws, float* __restrict__ out) {
    int tid = threadIdx.x;
    double v = ws[tid] + ws[tid + 64];
    v = wred(v);
    if (tid == 0) out[0] = (float)(v / (double)N_B);
}

extern "C" void kernel_launch(void* const* d_in, const int* in_sizes, int n_in,
                              void* d_out, int out_size, void* d_ws, size_t ws_size,
                              hipStream_t stream) {
    const float* seq = (const float*)d_in[0];   // input_sequence (128, 8192, 8)
    // d_in[1] = hidden_states — unused by the reference; never read.
    const float* lw  = (const float*)d_in[2];   // lag_weights (24,)
    const float* si  = (const float*)d_in[3];   // seasonal_importance (2,)
    float* out = (float*)d_out;
    double* ws = (double*)d_ws;                 // 128 doubles of scratch

    autocorr_batch_kernel<<<N_B, 256, 0, stream>>>(seq, lw, si, ws);
    final_reduce_kernel<<<1, 64, 0, stream>>>(ws, out);
}

// Round 2
// 1151.370 us; speedup vs baseline: 1.0095x; 1.0095x over previous
//
#include <hip/hip_runtime.h>
#include <math.h>

#define T_LEN 8192
#define N_B   128
#define N_F   8
#define NLAGS 24
#define CHUNK 1024
#define NCHK  8            // T_LEN / CHUNK
#define NPART 26           // 24 xy + S + Q

__device__ __forceinline__ double wred(double v) {
    #pragma unroll
    for (int o = 32; o > 0; o >>= 1) v += __shfl_down(v, o, 64);
    return v;
}

// K1: one block per (batch, chunk). Raw-space partial sums in double.
__global__ __launch_bounds__(256)
void partials_kernel(const float* __restrict__ seq, double* __restrict__ part) {
    __shared__ float  sx[CHUNK + NLAGS];   // 1048 floats, halo zero-padded
    __shared__ double sp[4][NPART];

    const int bc = blockIdx.x;             // 0..1023
    const int b  = bc >> 3;
    const int c  = bc & 7;
    const int t0 = c * CHUNK;
    const int tid  = threadIdx.x;
    const int wave = tid >> 6;
    const int lane = tid & 63;
    const size_t base = (size_t)b * T_LEN * N_F;

    // stage chunk + 24-halo (zero pad past T: makes ragged-window products 0)
    for (int idx = tid; idx < CHUNK + NLAGS; idx += 256) {
        int t = t0 + idx;
        sx[idx] = (t < T_LEN) ? seq[base + (size_t)t * N_F] : 0.0f;
    }
    __syncthreads();

    const int tl = tid * 4;                // 4 elements per thread
    float r[4 + NLAGS];
    #pragma unroll
    for (int j = 0; j < 4 + NLAGS; j++) r[j] = sx[tl + j];

    double s = 0.0, q = 0.0;
    #pragma unroll
    for (int j = 0; j < 4; j++) { double v = r[j]; s += v; q += v * v; }

    double xy[NLAGS];
    #pragma unroll
    for (int l = 0; l < NLAGS; l++) {
        double a = 0.0;
        #pragma unroll
        for (int j = 0; j < 4; j++) a += (double)r[j] * (double)r[j + l + 1];
        xy[l] = a;
    }

    // block-reduce 26 doubles
    #pragma unroll
    for (int k = 0; k < NLAGS; k++) {
        double v = wred(xy[k]);
        if (lane == 0) sp[wave][k] = v;
    }
    {
        double v = wred(s);
        if (lane == 0) sp[wave][24] = v;
        v = wred(q);
        if (lane == 0) sp[wave][25] = v;
    }
    __syncthreads();
    if (tid < NPART) {
        part[(size_t)bc * NPART + tid] =
            sp[0][tid] + sp[1][tid] + sp[2][tid] + sp[3][tid];
    }
}

// K2: one block per batch. Combine chunk partials, Pearson per lag, softmax.
__global__ __launch_bounds__(64)
void pearson_kernel(const double* __restrict__ part,
                    const float* __restrict__ seq,
                    const float* __restrict__ lw,
                    const float* __restrict__ si,
                    double* __restrict__ ws2) {
    __shared__ double red[NPART];
    __shared__ float  bnd[2][NLAGS];

    const int b = blockIdx.x;
    const int l = threadIdx.x;
    const size_t base = (size_t)b * T_LEN * N_F;

    if (l < NPART) {
        double a = 0.0;
        for (int c = 0; c < NCHK; c++)
            a += part[(size_t)((b << 3) + c) * NPART + l];
        red[l] = a;
    }
    if (l < NLAGS) {
        bnd[0][l] = seq[base + (size_t)l * N_F];
        bnd[1][l] = seq[base + (size_t)(T_LEN - 1 - l) * N_F];
    }
    __syncthreads();

    double contrib = 0.0;
    if (l < NLAGS) {
        const int lag = l + 1;
        const double S = red[24], Q = red[25];
        double ps = 0.0, pq = 0.0, ss = 0.0, sq = 0.0;
        for (int j = 0; j < lag; j++) {
            double xp = bnd[0][j], xs = bnd[1][j];
            ps += xp; pq += xp * xp;
            ss += xs; sq += xs * xs;
        }
        const double n  = (double)(T_LEN - lag);
        const double sx = S - ss;     // x window [0, T-lag)
        const double sy = S - ps;     // y window [lag, T)
        const double qx = Q - sq;
        const double qy = Q - pq;
        const double xy = red[l];
        const double num = xy - sx * sy / n;
        const double dx  = qx - sx * sx / n;
        const double dy  = qy - sy * sy / n;
        double r = num / (sqrt(dx) * sqrt(dy));
        r = fmin(1.0, fmax(-1.0, r));

        double m = -1e300;
        for (int k = 0; k < NLAGS; k++) m = fmax(m, (double)lw[k]);
        double wsum = 0.0;
        for (int k = 0; k < NLAGS; k++) wsum += exp((double)lw[k] - m);
        const double w = exp((double)lw[l] - m) / wsum;

        contrib = r * w;
        if (lag == 12) contrib += r * (double)si[0];
        if (lag == 24) contrib += r * (double)si[1];
    }
    contrib = wred(contrib);
    if (l == 0) ws2[b] = contrib;
}

__global__ __launch_bounds__(64)
void final_reduce_kernel(const double* __restrict__ ws2, float* __restrict__ out) {
    int tid = threadIdx.x;
    double v = ws2[tid] + ws2[tid + 64];
    v = wred(v);
    if (tid == 0) out[0] = (float)(v / (double)N_B);
}

extern "C" void kernel_launch(void* const* d_in, const int* in_sizes, int n_in,
                              void* d_out, int out_size, void* d_ws, size_t ws_size,
                              hipStream_t stream) {
    const float* seq = (const float*)d_in[0];   // (128, 8192, 8) fp32
    // d_in[1] = hidden_states — unused by the reference; never read.
    const float* lw  = (const float*)d_in[2];   // (24,)
    const float* si  = (const float*)d_in[3];   // (2,)
    float* out = (float*)d_out;

    double* part = (double*)d_ws;                           // 1024*26 doubles
    double* ws2  = part + (size_t)N_B * NCHK * NPART;       // 128 doubles

    partials_kernel<<<N_B * NCHK, 256, 0, stream>>>(seq, part);
    pearson_kernel<<<N_B, 64, 0, stream>>>(part, seq, lw, si, ws2);
    final_reduce_kernel<<<1, 64, 0, stream>>>(ws2, out);
}